// Round 11
// baseline (1749.695 us; speedup 1.0000x reference)
//
#include <hip/hip_runtime.h>
#include <math.h>
#include <stdint.h>

#define NN 50000
#define NE 300000
#define NT4 200000  // NN*4 (dst,type) segments
#define NG 128
#define NSTEP 8
#define MPAD 50048  // 782*64
#define SCB 196     // ceil(NN/256)
#define SCB2 782    // ceil(NT4/256)
#define PCH 8
#define EM 64       // k_eagg M tile
#define ECAP 896    // LDS-staged edge capacity per tile (mean 384)

typedef __attribute__((ext_vector_type(8))) short bf16x8;
typedef __attribute__((ext_vector_type(8))) unsigned short u16x8;
typedef __attribute__((ext_vector_type(4))) float f32x4;
typedef unsigned short u16;
typedef unsigned int u32;

__device__ __forceinline__ float b2f(u16 u) {
  union { u32 i; float f; } c; c.i = ((u32)u) << 16; return c.f;
}
__device__ __forceinline__ u16 f2b(float f) {
  union { float f; u32 i; } c; c.f = f;
  u32 x = c.i;
  u32 r = (x + 0x7fffu + ((x >> 16) & 1u)) >> 16;
  return (u16)r;
}

__device__ __forceinline__ void load_lds16(const void* g, void* l) {
  __builtin_amdgcn_global_load_lds((const __attribute__((address_space(1))) u32*)g,
                                   (__attribute__((address_space(3))) u32*)l, 16, 0, 0);
}

// ---------------- weight prep ----------------
// Wt_e[t*256+col][k] = W_e[t][k][col]
__global__ void k_conv_we(const float* __restrict__ W_e, u16* __restrict__ Wt) {
  int i = blockIdx.x * 256 + threadIdx.x;  // 1024*256
  int c = i >> 8, d = i & 255;
  Wt[c * 256 + d] = f2b(W_e[(c >> 8) * 65536 + d * 256 + (c & 255)]);
}
// RZ weights: variant AH: k<256 -> W_ih[k][n], k>=256 -> W_hh[k-256][n]
//             variant HA: k<256 -> W_hh[k][n], k>=256 -> W_ih[k-256][n]
__global__ void k_conv_rz(const float* __restrict__ W_ih, const float* __restrict__ W_hh,
                          u16* __restrict__ ah, u16* __restrict__ ha) {
  int i = blockIdx.x * 256 + threadIdx.x;  // 512*512
  int n = i >> 9, k = i & 511;
  float va = (k < 256) ? W_ih[k * 768 + n] : W_hh[(k - 256) * 768 + n];
  float vh = (k < 256) ? W_hh[k * 768 + n] : W_ih[(k - 256) * 768 + n];
  ah[n * 512 + k] = f2b(va);
  ha[n * 512 + k] = f2b(vh);
}
// n-gate weights: Wt[n][k] = W[k][512+n]
__global__ void k_conv_n(const float* __restrict__ W, u16* __restrict__ Wt) {
  int i = blockIdx.x * 256 + threadIdx.x;  // 256*256
  int n = i >> 8, k = i & 255;
  Wt[n * 256 + k] = f2b(W[k * 768 + 512 + n]);
}
__global__ void k_brz(const float* __restrict__ b_ih, const float* __restrict__ b_hh,
                      float* __restrict__ b_rz) {
  int i = blockIdx.x * 256 + threadIdx.x;
  if (i < 512) b_rz[i] = b_ih[i] + b_hh[i];
}

// acat layout per row (768 cols): [hbA (256) | ab (256) | hbB (256)]
__global__ void k_init_h(const float* __restrict__ feat, u16* __restrict__ acat) {
  int i = blockIdx.x * 256 + threadIdx.x;  // MPAD*64
  int n = i >> 6, d = (i & 63) << 2;
  ushort4 o;
  if (n < NN) {
    float4 v = *(const float4*)(feat + (size_t)n * 1024 + d);
    o.x = f2b(v.x); o.y = f2b(v.y); o.z = f2b(v.z); o.w = f2b(v.w);
  } else {
    o.x = o.y = o.z = o.w = 0;
  }
  *(ushort4*)(acat + (size_t)n * 768 + d) = o;
}

// ---------------- CSR build over (dst*4+type) ----------------
__global__ void k_hist(const int* __restrict__ dst, const int* __restrict__ ety,
                       int* __restrict__ deg2) {
  int e = blockIdx.x * 256 + threadIdx.x;
  if (e < NE) atomicAdd(&deg2[dst[e] * 4 + ety[e]], 1);
}
__global__ void k_scan1(const int* __restrict__ deg2, int* __restrict__ part, int* __restrict__ bsum) {
  __shared__ int sh[256];
  int b = blockIdx.x, t = threadIdx.x;
  int i = b * 256 + t;
  int v = (i < NT4) ? deg2[i] : 0;
  sh[t] = v;
  __syncthreads();
  for (int off = 1; off < 256; off <<= 1) {
    int tmp = (t >= off) ? sh[t - off] : 0;
    __syncthreads();
    sh[t] += tmp;
    __syncthreads();
  }
  if (i < NT4) part[i] = sh[t] - v;
  if (t == 255) bsum[b] = sh[255];
}
__global__ void k_scan2(const int* __restrict__ bsum, int* __restrict__ boff) {
  __shared__ int sh[1024];
  int t = threadIdx.x;
  int v = (t < SCB2) ? bsum[t] : 0;
  sh[t] = v;
  __syncthreads();
  for (int off = 1; off < 1024; off <<= 1) {
    int tmp = (t >= off) ? sh[t - off] : 0;
    __syncthreads();
    sh[t] += tmp;
    __syncthreads();
  }
  boff[t] = sh[t] - v;
  if (t == 1023) boff[1024] = sh[1023];
}
__global__ void k_scan3(const int* __restrict__ part, const int* __restrict__ boff, int* __restrict__ rp2) {
  int i = blockIdx.x * 256 + threadIdx.x;
  if (i < NT4) rp2[i] = part[i] + boff[i >> 8];
  if (i == NT4) rp2[NT4] = boff[1024];
}
__global__ void k_scatter(const int* __restrict__ src, const int* __restrict__ dst,
                          const int* __restrict__ ety, const int* __restrict__ rp2,
                          int* __restrict__ cursor2, int* __restrict__ esrc) {
  int e = blockIdx.x * 256 + threadIdx.x;
  if (e < NE) {
    int seg = dst[e] * 4 + ety[e];
    int p = rp2[seg] + atomicAdd(&cursor2[seg], 1);
    esrc[p] = src[e];
  }
}
__global__ void k_cnt2(const int* __restrict__ deg2, ushort4* __restrict__ cnt2) {
  int v = blockIdx.x * 256 + threadIdx.x;
  if (v >= MPAD) return;
  ushort4 o;
  if (v < NN) {
    o.x = (u16)deg2[v * 4 + 0]; o.y = (u16)deg2[v * 4 + 1];
    o.z = (u16)deg2[v * 4 + 2]; o.w = (u16)deg2[v * 4 + 3];
  } else {
    o.x = o.y = o.z = o.w = 0;
  }
  cnt2[v] = o;
}
__global__ void k_gstart(const int* __restrict__ n2g, int* __restrict__ gstart) {
  int n = blockIdx.x * 256 + threadIdx.x;
  if (n >= NN) return;
  int g = n2g[n];
  int gp = (n == 0) ? -1 : n2g[n - 1];
  for (int x = gp + 1; x <= g; ++x) gstart[x] = n;
  if (n == NN - 1)
    for (int x = g + 1; x <= NG; ++x) gstart[x] = NN;
}

// ---------------- fused aggregate + e-GEMM (i_n moved to k_gruF) ----------------
__global__ __launch_bounds__(512, 4) void k_eagg(
    const u16* __restrict__ acat, int hboff,
    const int* __restrict__ rp2, const int* __restrict__ esrc,
    const u16* __restrict__ Wt_e,
    const ushort4* __restrict__ cnt2, const float* __restrict__ b_e,
    u16* __restrict__ acat_out) {
  __shared__ __align__(16) char Ss[EM * 512];    // 32KB: [64 rows][256 k] bf16, XOR-swizzled
  __shared__ __align__(16) char Bs[256 * 128];   // 32KB: [256 n][64 k] bf16, XOR-swizzled
  __shared__ int Es[ECAP];
  __shared__ int Rp[257];
  const int tid = threadIdx.x;
  const int wv = tid >> 6, l = tid & 63;
  const int hw = tid >> 5, lw = tid & 31;
  const int m0 = blockIdx.x * EM;
  const int fr = l & 15, kq = l >> 4;
  const int wm = (wv >> 2) * 32, wn = (wv & 3) * 64;

  const int base4 = m0 * 4;
  const int e0 = rp2[base4];
  for (int i = tid; i <= 256; i += 512) {
    int idx = base4 + i;
    if (idx > NT4) idx = NT4;
    Rp[i] = rp2[idx] - e0;
  }
  {
    int idxe = base4 + 256;
    if (idxe > NT4) idxe = NT4;
    int ecnt = rp2[idxe] - e0;
    int ecl = ecnt < ECAP ? ecnt : ECAP;
    for (int i = tid; i < ecl; i += 512) Es[i] = esrc[e0 + i] * 768 + hboff;
  }
  __syncthreads();

  f32x4 acc[2][4];
#pragma unroll
  for (int m = 0; m < 2; ++m)
#pragma unroll
    for (int n = 0; n < 4; ++n) acc[m][n] = (f32x4){0.f, 0.f, 0.f, 0.f};

  for (int t = 0; t < 4; ++t) {
    if (t > 0) __syncthreads();
    int cc[4], ee[4];
#pragma unroll
    for (int rr = 0; rr < 4; ++rr) {
      int li = (hw * 4 + rr) * 4 + t;
      cc[rr] = Rp[li];
      ee[rr] = Rp[li + 1];
    }
    float ar[4][8];
#pragma unroll
    for (int rr = 0; rr < 4; ++rr)
#pragma unroll
      for (int q = 0; q < 8; ++q) ar[rr][q] = 0.f;
    bool more = (cc[0] < ee[0]) | (cc[1] < ee[1]) | (cc[2] < ee[2]) | (cc[3] < ee[3]);
    while (more) {
      u16x8 v[4];
      bool p[4];
#pragma unroll
      for (int rr = 0; rr < 4; ++rr) {
        p[rr] = cc[rr] < ee[rr];
        if (p[rr]) {
          int rel = cc[rr];
          int off = (rel < ECAP) ? Es[rel] : (esrc[e0 + rel] * 768 + hboff);
          v[rr] = *(const u16x8*)(acat + (size_t)off + lw * 8);
        }
      }
#pragma unroll
      for (int rr = 0; rr < 4; ++rr) {
        if (p[rr]) {
#pragma unroll
          for (int q = 0; q < 8; ++q) ar[rr][q] += b2f(v[rr][q]);
          cc[rr]++;
        }
      }
      more = (cc[0] < ee[0]) | (cc[1] < ee[1]) | (cc[2] < ee[2]) | (cc[3] < ee[3]);
    }
#pragma unroll
    for (int rr = 0; rr < 4; ++rr) {
      int row = hw * 4 + rr;
      u16x8 o;
#pragma unroll
      for (int q = 0; q < 8; ++q) o[q] = f2b(ar[rr][q]);
      *(u16x8*)(Ss + row * 512 + ((lw * 16) ^ ((row & 7) << 4))) = o;
    }

    const u16* Bw = Wt_e + (size_t)t * 65536;
    for (int kc = 0; kc < 4; ++kc) {
      __syncthreads();
#pragma unroll
      for (int pph = 0; pph < 4; ++pph) {
        int brow = pph * 64 + (tid >> 3);
        int ks = kc * 64 + (((tid & 7) ^ (brow & 7)) << 3);
        load_lds16(Bw + (size_t)brow * 256 + ks, Bs + pph * 8192 + wv * 1024);
      }
      asm volatile("s_waitcnt vmcnt(0)" ::: "memory");
      __syncthreads();
#pragma unroll
      for (int kk = 0; kk < 64; kk += 32) {
        bf16x8 af[2], bfr[4];
        int kb = (kk + kq * 8) * 2;
        int ka = (kc * 64 + kk + kq * 8) * 2;
#pragma unroll
        for (int m = 0; m < 2; ++m) {
          int R = wm + m * 16 + fr;
          af[m] = *(const bf16x8*)(Ss + R * 512 + (ka ^ ((R & 7) << 4)));
        }
#pragma unroll
        for (int n = 0; n < 4; ++n) {
          int R = wn + n * 16 + fr;
          bfr[n] = *(const bf16x8*)(Bs + R * 128 + (kb ^ ((R & 7) << 4)));
        }
#pragma unroll
        for (int m = 0; m < 2; ++m)
#pragma unroll
          for (int n = 0; n < 4; ++n)
            acc[m][n] = __builtin_amdgcn_mfma_f32_16x16x32_bf16(af[m], bfr[n], acc[m][n], 0, 0, 0);
      }
    }
  }
  __syncthreads();

  float bev[4][4];
#pragma unroll
  for (int n = 0; n < 4; ++n)
#pragma unroll
    for (int t = 0; t < 4; ++t) bev[n][t] = b_e[t * 256 + wn + n * 16 + fr];
#pragma unroll
  for (int m = 0; m < 2; ++m) {
#pragma unroll
    for (int j = 0; j < 4; ++j) {
      int r = wm + m * 16 + kq * 4 + j;
      int v = m0 + r;
      ushort4 c4 = cnt2[v];
      float c0 = c4.x, c1 = c4.y, c2 = c4.z, c3 = c4.w;
#pragma unroll
      for (int n = 0; n < 4; ++n) {
        int col = wn + n * 16 + fr;
        float val = acc[m][n][j] + c0 * bev[n][0] + c1 * bev[n][1] + c2 * bev[n][2] + c3 * bev[n][3];
        acat_out[(size_t)v * 768 + 256 + col] = f2b(val);
      }
    }
  }
}

// ---------------- fully fused GRU: r,z,i_n,h_n GEMMs + combine (pipelined) ----------------
// 512 threads, 8 waves (2M x 4N), BM=64, N=256 output cols. A-panel [a|h] (64x512)
// staged ONCE into As (64KB). B streamed in BK=32 chunks, double-buffered (2x32KB),
// counted-vmcnt pipeline (r10-proven). h_old re-read from As. Epilogue combines in-register.
__global__ __launch_bounds__(512, 2) void k_gruF(
    const u16* __restrict__ acat, int rzoff, int aoff, int hoff, int hnewoff,
    const u16* __restrict__ Wrz, const u16* __restrict__ Wt_inhn,
    const float* __restrict__ b_rz, const float* __restrict__ b_ih,
    const float* __restrict__ b_hh, u16* __restrict__ acat_out) {
  __shared__ __align__(16) char As[8][64 * 128];  // 8 k-chunks x 8KB = 64KB
  __shared__ __align__(16) char BsB[2][32768];    // 2 x 32KB (512 rows x 32k)
  const int tid = threadIdx.x;
  const int wv = tid >> 6, l = tid & 63;
  const int m0 = blockIdx.x * 64;
  const int fr = l & 15, kq = l >> 4;
  const int wm = (wv >> 2) * 32, wn = (wv & 3) * 64;
  const int arow = tid >> 3, acl = tid & 7;  // As staging
  const int brow0 = tid >> 2, bs = tid & 3;  // B staging

  // stage full A-panel (8 chunks, 1 load/thread each; lands before first barrier)
#pragma unroll
  for (int ck = 0; ck < 8; ++ck) {
    load_lds16(acat + (size_t)(m0 + arow) * 768 + rzoff + ck * 64 + ((acl ^ (arow & 7)) << 3),
               As[ck] + wv * 1024);
  }

  auto stageB = [&](int buf, const u16* W, int ldw, int kc) {
#pragma unroll
    for (int p2 = 0; p2 < 4; ++p2) {
      int brow = p2 * 128 + brow0;
      int mm = (brow & 3) ^ ((brow >> 2) & 3);
      load_lds16(W + (size_t)brow * ldw + kc * 32 + ((bs ^ mm) << 3),
                 BsB[buf] + p2 * 8192 + wv * 1024);
    }
  };
  stageB(0, Wrz, 512, 0);

  f32x4 ar_[2][4], az_[2][4], ai_[2][4], ah_[2][4];
#pragma unroll
  for (int m = 0; m < 2; ++m)
#pragma unroll
    for (int n = 0; n < 4; ++n) {
      ar_[m][n] = (f32x4){0.f, 0.f, 0.f, 0.f};
      az_[m][n] = (f32x4){0.f, 0.f, 0.f, 0.f};
      ai_[m][n] = (f32x4){0.f, 0.f, 0.f, 0.f};
      ah_[m][n] = (f32x4){0.f, 0.f, 0.f, 0.f};
    }

  // ---- phase 1: r,z over K=512 (16 chunks of BK=32) ----
  for (int ki = 0; ki < 16; ++ki) {
    const int cur = ki & 1;
    if (ki < 15) stageB(cur ^ 1, Wrz, 512, ki + 1);
    else stageB(cur ^ 1, Wt_inhn, 256, 0);  // prefetch phase-2 chunk 0
    asm volatile("s_waitcnt vmcnt(4)" ::: "memory");
    __builtin_amdgcn_s_barrier();
    __builtin_amdgcn_sched_barrier(0);
    const char* Bs = BsB[cur];
    const int ck = ki >> 1;
    const int kkb = (((ki & 1) << 5) + (kq << 3)) << 1;
    bf16x8 af[2], br4[4], bz4[4];
#pragma unroll
    for (int m = 0; m < 2; ++m) {
      int R = wm + m * 16 + fr;
      af[m] = *(const bf16x8*)(As[ck] + R * 128 + (kkb ^ ((R & 7) << 4)));
    }
#pragma unroll
    for (int n = 0; n < 4; ++n) {
      int Rr = wn + n * 16 + fr;
      int mr = (Rr & 3) ^ ((Rr >> 2) & 3);
      br4[n] = *(const bf16x8*)(Bs + Rr * 64 + ((kq ^ mr) << 4));
      int Rz = Rr + 256;
      int mz = (Rz & 3) ^ ((Rz >> 2) & 3);
      bz4[n] = *(const bf16x8*)(Bs + Rz * 64 + ((kq ^ mz) << 4));
    }
#pragma unroll
    for (int m = 0; m < 2; ++m)
#pragma unroll
      for (int n = 0; n < 4; ++n) {
        ar_[m][n] = __builtin_amdgcn_mfma_f32_16x16x32_bf16(af[m], br4[n], ar_[m][n], 0, 0, 0);
        az_[m][n] = __builtin_amdgcn_mfma_f32_16x16x32_bf16(af[m], bz4[n], az_[m][n], 0, 0, 0);
      }
    asm volatile("s_waitcnt lgkmcnt(0)" ::: "memory");
    __builtin_amdgcn_sched_barrier(0);
    __builtin_amdgcn_s_barrier();
  }

  // ---- phase 2: i_n (A=a) and h_n (A=h) over K=256 (8 chunks) ----
  for (int kj = 0; kj < 8; ++kj) {
    const int cur = kj & 1;
    if (kj < 7) {
      stageB(cur ^ 1, Wt_inhn, 256, kj + 1);
      asm volatile("s_waitcnt vmcnt(4)" ::: "memory");
    } else {
      asm volatile("s_waitcnt vmcnt(0)" ::: "memory");
    }
    __builtin_amdgcn_s_barrier();
    __builtin_amdgcn_sched_barrier(0);
    const char* Bs = BsB[cur];
    const int ckA = (aoff >> 6) + (kj >> 1), ckH = (hoff >> 6) + (kj >> 1);
    const int kkb = (((kj & 1) << 5) + (kq << 3)) << 1;
    bf16x8 afA[2], afH[2], bi4[4], bh4[4];
#pragma unroll
    for (int m = 0; m < 2; ++m) {
      int R = wm + m * 16 + fr;
      afA[m] = *(const bf16x8*)(As[ckA] + R * 128 + (kkb ^ ((R & 7) << 4)));
      afH[m] = *(const bf16x8*)(As[ckH] + R * 128 + (kkb ^ ((R & 7) << 4)));
    }
#pragma unroll
    for (int n = 0; n < 4; ++n) {
      int Ri = wn + n * 16 + fr;
      int mi = (Ri & 3) ^ ((Ri >> 2) & 3);
      bi4[n] = *(const bf16x8*)(Bs + Ri * 64 + ((kq ^ mi) << 4));
      int Rh = Ri + 256;
      int mh = (Rh & 3) ^ ((Rh >> 2) & 3);
      bh4[n] = *(const bf16x8*)(Bs + Rh * 64 + ((kq ^ mh) << 4));
    }
#pragma unroll
    for (int m = 0; m < 2; ++m)
#pragma unroll
      for (int n = 0; n < 4; ++n) {
        ai_[m][n] = __builtin_amdgcn_mfma_f32_16x16x32_bf16(afA[m], bi4[n], ai_[m][n], 0, 0, 0);
        ah_[m][n] = __builtin_amdgcn_mfma_f32_16x16x32_bf16(afH[m], bh4[n], ah_[m][n], 0, 0, 0);
      }
    asm volatile("s_waitcnt lgkmcnt(0)" ::: "memory");
    __builtin_amdgcn_sched_barrier(0);
    __builtin_amdgcn_s_barrier();
  }

  // ---- epilogue: in-register GRU combine; h_old from As ----
  float brb[4], bzb[4], bib[4], bhb[4];
#pragma unroll
  for (int n = 0; n < 4; ++n) {
    int c = wn + n * 16 + fr;
    brb[n] = b_rz[c];
    bzb[n] = b_rz[256 + c];
    bib[n] = b_ih[512 + c];
    bhb[n] = b_hh[512 + c];
  }
#pragma unroll
  for (int m = 0; m < 2; ++m) {
#pragma unroll
    for (int j = 0; j < 4; ++j) {
      int rl = wm + m * 16 + kq * 4 + j;
      int row = m0 + rl;
#pragma unroll
      for (int n = 0; n < 4; ++n) {
        int c = wn + n * 16 + fr;
        float r = 1.f / (1.f + expf(-(ar_[m][n][j] + brb[n])));
        float z = 1.f / (1.f + expf(-(az_[m][n][j] + bzb[n])));
        float in_ = ai_[m][n][j] + bib[n];
        float hn_ = ah_[m][n][j] + bhb[n];
        int ckh = (hoff + c) >> 6, kkh = c & 63;
        float ho = b2f(*(const u16*)(As[ckh] + rl * 128 + ((kkh * 2) ^ ((rl & 7) << 4))));
        float ng = tanhf(in_ + r * hn_);
        acat_out[(size_t)row * 768 + hnewoff + c] = f2b((1.f - z) * ng + z * ho);
      }
    }
  }
}

// ---------------- pooling + head ----------------
__global__ __launch_bounds__(256) void k_pool(const u16* __restrict__ hb, const float* __restrict__ feat,
                                              const int* __restrict__ gstart, float* __restrict__ pooled) {
  int g = blockIdx.x, ch = blockIdx.y, t = threadIdx.x;
  int s = gstart[g], e = gstart[g + 1];
  int tot = e - s;
  int per = (tot + PCH - 1) / PCH;
  int ns = s + ch * per;
  int ne = ns + per < e ? ns + per : e;
  if (ns >= ne) return;
  int c = t << 2;
  float a0 = 0.f, a1 = 0.f, a2 = 0.f, a3 = 0.f;
  if (c < 256) {
    for (int n = ns; n < ne; ++n) {
      ushort4 u = *(const ushort4*)(hb + (size_t)n * 768 + c);
      a0 += b2f(u.x); a1 += b2f(u.y); a2 += b2f(u.z); a3 += b2f(u.w);
    }
  } else {
    for (int n = ns; n < ne; ++n) {
      float4 v = *(const float4*)(feat + (size_t)n * 1024 + c);
      a0 += v.x; a1 += v.y; a2 += v.z; a3 += v.w;
    }
  }
  atomicAdd(&pooled[g * 1024 + c], a0);
  atomicAdd(&pooled[g * 1024 + c + 1], a1);
  atomicAdd(&pooled[g * 1024 + c + 2], a2);
  atomicAdd(&pooled[g * 1024 + c + 3], a3);
}

__global__ __launch_bounds__(256) void k_head(const float* __restrict__ pooled,
                                              const int* __restrict__ gstart,
                                              const float* __restrict__ W1, const float* __restrict__ b1,
                                              const float* __restrict__ W2, const float* __restrict__ b2,
                                              float* __restrict__ out) {
  __shared__ float sp[1024];
  __shared__ float red[256];
  int g = blockIdx.x, t = threadIdx.x;
  float inv = 1.f / fmaxf((float)(gstart[g + 1] - gstart[g]), 1.f);
  for (int i = t; i < 1024; i += 256) sp[i] = pooled[g * 1024 + i] * inv;
  __syncthreads();
  float acc = b1[t];
  for (int k = 0; k < 1024; ++k) acc += sp[k] * W1[k * 256 + t];
  float hc = fmaxf(acc, 0.f);
  red[t] = hc * W2[t];
  __syncthreads();
  for (int s2 = 128; s2 > 0; s2 >>= 1) {
    if (t < s2) red[t] += red[t + s2];
    __syncthreads();
  }
  if (t == 0) out[g] = 1.f / (1.f + expf(-(red[0] + b2[0])));
}

extern "C" void kernel_launch(void* const* d_in, const int* in_sizes, int n_in, void* d_out, int out_size,
                              void* d_ws, size_t ws_size, hipStream_t stream) {
  const float* feat = (const float*)d_in[0];
  const float* W_e = (const float*)d_in[1];
  const float* b_e = (const float*)d_in[2];
  const float* W_ih = (const float*)d_in[3];
  const float* W_hh = (const float*)d_in[4];
  const float* b_ih = (const float*)d_in[5];
  const float* b_hh = (const float*)d_in[6];
  const float* W1 = (const float*)d_in[7];
  const float* b1 = (const float*)d_in[8];
  const float* W2 = (const float*)d_in[9];
  const float* b2 = (const float*)d_in[10];
  const int* src = (const int*)d_in[11];
  const int* dst = (const int*)d_in[12];
  const int* ety = (const int*)d_in[13];
  const int* n2g = (const int*)d_in[14];

  char* p = (char*)d_ws;
  auto alloc = [&](size_t b) { char* r = p; p += (b + 255) & ~(size_t)255; return r; };
  u16* acat = (u16*)alloc((size_t)MPAD * 768 * 2);  // [hbA | ab | hbB]
  u16* Wt_e = (u16*)alloc(1024 * 256 * 2);
  u16* Wt_rz_ah = (u16*)alloc(512 * 512 * 2);
  u16* Wt_rz_ha = (u16*)alloc(512 * 512 * 2);
  u16* Wt_inhn = (u16*)alloc(512 * 256 * 2);  // rows 0-255: W_in, 256-511: W_hn
  float* b_rz = (float*)alloc(512 * 4);
  int* deg2 = (int*)alloc((size_t)NT4 * 4);
  int* part = (int*)alloc((size_t)NT4 * 4);
  int* bsum = (int*)alloc((size_t)SCB2 * 4);
  int* boff = (int*)alloc(1025 * 4);
  int* rp2 = (int*)alloc((size_t)(NT4 + 1) * 4);
  int* cursor2 = (int*)alloc((size_t)NT4 * 4);
  int* esrc = (int*)alloc((size_t)NE * 4);
  ushort4* cnt2 = (ushort4*)alloc((size_t)MPAD * 8);
  int* gstart = (int*)alloc((size_t)(NG + 1) * 4);
  float* pooled = (float*)alloc((size_t)NG * 1024 * 4);

  hipMemsetAsync(deg2, 0, (size_t)NT4 * 4, stream);
  hipMemsetAsync(cursor2, 0, (size_t)NT4 * 4, stream);
  hipMemsetAsync(pooled, 0, (size_t)NG * 1024 * 4, stream);

  k_conv_we<<<1024, 256, 0, stream>>>(W_e, Wt_e);
  k_conv_rz<<<1024, 256, 0, stream>>>(W_ih, W_hh, Wt_rz_ah, Wt_rz_ha);
  k_conv_n<<<256, 256, 0, stream>>>(W_ih, Wt_inhn);
  k_conv_n<<<256, 256, 0, stream>>>(W_hh, Wt_inhn + 256 * 256);
  k_brz<<<2, 256, 0, stream>>>(b_ih, b_hh, b_rz);
  k_init_h<<<MPAD / 4, 256, 0, stream>>>(feat, acat);
  k_hist<<<(NE + 255) / 256, 256, 0, stream>>>(dst, ety, deg2);
  k_scan1<<<SCB2, 256, 0, stream>>>(deg2, part, bsum);
  k_scan2<<<1, 1024, 0, stream>>>(bsum, boff);
  k_scan3<<<SCB2 + 1, 256, 0, stream>>>(part, boff, rp2);
  k_scatter<<<(NE + 255) / 256, 256, 0, stream>>>(src, dst, ety, rp2, cursor2, esrc);
  k_cnt2<<<(MPAD + 255) / 256, 256, 0, stream>>>(deg2, cnt2);
  k_gstart<<<SCB, 256, 0, stream>>>(n2g, gstart);

  const int GY = MPAD / 64;  // 782
  for (int s = 0; s < NSTEP; ++s) {
    int hboff = (s & 1) ? 512 : 0;
    int hnewoff = 512 - hboff;
    int rzoff = (s & 1) ? 256 : 0;
    int aoff = (s & 1) ? 0 : 256;   // k-offset of ab within the rz panel
    int hoff = (s & 1) ? 256 : 0;   // k-offset of hb within the rz panel
    const u16* Wrz = (s & 1) ? Wt_rz_ah : Wt_rz_ha;
    // fused gather + e-GEMM -> ab
    k_eagg<<<MPAD / EM, 512, 0, stream>>>(acat, hboff, rp2, esrc, Wt_e, cnt2, b_e, acat);
    // fused r,z,i_n,h_n GEMMs + GRU combine -> hnew (pipelined, no intermediates)
    k_gruF<<<GY, 512, 0, stream>>>(acat, rzoff, aoff, hoff, hnewoff, Wrz, Wt_inhn,
                                   b_rz, b_ih, b_hh, acat);
  }

  // after step 7 (odd), final h is in hbA (offset 0)
  k_pool<<<dim3(NG, PCH), 256, 0, stream>>>(acat, feat, gstart, pooled);
  k_head<<<NG, 256, 0, stream>>>(pooled, gstart, W1, b1, W2, b2, (float*)d_out);
}

// Round 12
// 1673.147 us; speedup vs baseline: 1.0458x; 1.0458x over previous
//
#include <hip/hip_runtime.h>
#include <math.h>
#include <stdint.h>

#define NN 50000
#define NE 300000
#define NT4 200000  // NN*4 (dst,type) segments
#define NG 128
#define NSTEP 8
#define MPAD 50048  // 782*64
#define SCB 196     // ceil(NN/256)
#define SCB2 782    // ceil(NT4/256)
#define PCH 8
#define EM 64       // k_eagg M tile
#define ECAP 896    // LDS-staged edge capacity per tile (mean 384)

typedef __attribute__((ext_vector_type(8))) short bf16x8;
typedef __attribute__((ext_vector_type(8))) unsigned short u16x8;
typedef __attribute__((ext_vector_type(4))) float f32x4;
typedef unsigned short u16;
typedef unsigned int u32;

__device__ __forceinline__ float b2f(u16 u) {
  union { u32 i; float f; } c; c.i = ((u32)u) << 16; return c.f;
}
__device__ __forceinline__ u16 f2b(float f) {
  union { float f; u32 i; } c; c.f = f;
  u32 x = c.i;
  u32 r = (x + 0x7fffu + ((x >> 16) & 1u)) >> 16;
  return (u16)r;
}

__device__ __forceinline__ void load_lds16(const void* g, void* l) {
  __builtin_amdgcn_global_load_lds((const __attribute__((address_space(1))) u32*)g,
                                   (__attribute__((address_space(3))) u32*)l, 16, 0, 0);
}

// ---------------- weight prep ----------------
// Wt_e[t*256+col][k] = W_e[t][k][col]
__global__ void k_conv_we(const float* __restrict__ W_e, u16* __restrict__ Wt) {
  int i = blockIdx.x * 256 + threadIdx.x;  // 1024*256
  int c = i >> 8, d = i & 255;
  Wt[c * 256 + d] = f2b(W_e[(c >> 8) * 65536 + d * 256 + (c & 255)]);
}
// RZ weights: variant AH: k<256 -> W_ih[k][n], k>=256 -> W_hh[k-256][n]
//             variant HA: k<256 -> W_hh[k][n], k>=256 -> W_ih[k-256][n]
__global__ void k_conv_rz(const float* __restrict__ W_ih, const float* __restrict__ W_hh,
                          u16* __restrict__ ah, u16* __restrict__ ha) {
  int i = blockIdx.x * 256 + threadIdx.x;  // 512*512
  int n = i >> 9, k = i & 511;
  float va = (k < 256) ? W_ih[k * 768 + n] : W_hh[(k - 256) * 768 + n];
  float vh = (k < 256) ? W_hh[k * 768 + n] : W_ih[(k - 256) * 768 + n];
  ah[n * 512 + k] = f2b(va);
  ha[n * 512 + k] = f2b(vh);
}
// n-gate weights: Wt[n][k] = W[k][512+n]
__global__ void k_conv_n(const float* __restrict__ W, u16* __restrict__ Wt) {
  int i = blockIdx.x * 256 + threadIdx.x;  // 256*256
  int n = i >> 8, k = i & 255;
  Wt[n * 256 + k] = f2b(W[k * 768 + 512 + n]);
}
__global__ void k_brz(const float* __restrict__ b_ih, const float* __restrict__ b_hh,
                      float* __restrict__ b_rz) {
  int i = blockIdx.x * 256 + threadIdx.x;
  if (i < 512) b_rz[i] = b_ih[i] + b_hh[i];
}

// acat layout per row (768 cols): [hbA (256) | ab (256) | hbB (256)]
__global__ void k_init_h(const float* __restrict__ feat, u16* __restrict__ acat) {
  int i = blockIdx.x * 256 + threadIdx.x;  // MPAD*64
  int n = i >> 6, d = (i & 63) << 2;
  ushort4 o;
  if (n < NN) {
    float4 v = *(const float4*)(feat + (size_t)n * 1024 + d);
    o.x = f2b(v.x); o.y = f2b(v.y); o.z = f2b(v.z); o.w = f2b(v.w);
  } else {
    o.x = o.y = o.z = o.w = 0;
  }
  *(ushort4*)(acat + (size_t)n * 768 + d) = o;
}

// ---------------- CSR build over (dst*4+type) ----------------
__global__ void k_hist(const int* __restrict__ dst, const int* __restrict__ ety,
                       int* __restrict__ deg2) {
  int e = blockIdx.x * 256 + threadIdx.x;
  if (e < NE) atomicAdd(&deg2[dst[e] * 4 + ety[e]], 1);
}
__global__ void k_scan1(const int* __restrict__ deg2, int* __restrict__ part, int* __restrict__ bsum) {
  __shared__ int sh[256];
  int b = blockIdx.x, t = threadIdx.x;
  int i = b * 256 + t;
  int v = (i < NT4) ? deg2[i] : 0;
  sh[t] = v;
  __syncthreads();
  for (int off = 1; off < 256; off <<= 1) {
    int tmp = (t >= off) ? sh[t - off] : 0;
    __syncthreads();
    sh[t] += tmp;
    __syncthreads();
  }
  if (i < NT4) part[i] = sh[t] - v;
  if (t == 255) bsum[b] = sh[255];
}
__global__ void k_scan2(const int* __restrict__ bsum, int* __restrict__ boff) {
  __shared__ int sh[1024];
  int t = threadIdx.x;
  int v = (t < SCB2) ? bsum[t] : 0;
  sh[t] = v;
  __syncthreads();
  for (int off = 1; off < 1024; off <<= 1) {
    int tmp = (t >= off) ? sh[t - off] : 0;
    __syncthreads();
    sh[t] += tmp;
    __syncthreads();
  }
  boff[t] = sh[t] - v;
  if (t == 1023) boff[1024] = sh[1023];
}
__global__ void k_scan3(const int* __restrict__ part, const int* __restrict__ boff, int* __restrict__ rp2) {
  int i = blockIdx.x * 256 + threadIdx.x;
  if (i < NT4) rp2[i] = part[i] + boff[i >> 8];
  if (i == NT4) rp2[NT4] = boff[1024];
}
__global__ void k_scatter(const int* __restrict__ src, const int* __restrict__ dst,
                          const int* __restrict__ ety, const int* __restrict__ rp2,
                          int* __restrict__ cursor2, int* __restrict__ esrc) {
  int e = blockIdx.x * 256 + threadIdx.x;
  if (e < NE) {
    int seg = dst[e] * 4 + ety[e];
    int p = rp2[seg] + atomicAdd(&cursor2[seg], 1);
    esrc[p] = src[e];
  }
}
__global__ void k_cnt2(const int* __restrict__ deg2, ushort4* __restrict__ cnt2) {
  int v = blockIdx.x * 256 + threadIdx.x;
  if (v >= MPAD) return;
  ushort4 o;
  if (v < NN) {
    o.x = (u16)deg2[v * 4 + 0]; o.y = (u16)deg2[v * 4 + 1];
    o.z = (u16)deg2[v * 4 + 2]; o.w = (u16)deg2[v * 4 + 3];
  } else {
    o.x = o.y = o.z = o.w = 0;
  }
  cnt2[v] = o;
}
__global__ void k_gstart(const int* __restrict__ n2g, int* __restrict__ gstart) {
  int n = blockIdx.x * 256 + threadIdx.x;
  if (n >= NN) return;
  int g = n2g[n];
  int gp = (n == 0) ? -1 : n2g[n - 1];
  for (int x = gp + 1; x <= g; ++x) gstart[x] = n;
  if (n == NN - 1)
    for (int x = g + 1; x <= NG; ++x) gstart[x] = NN;
}

// ---------------- fused aggregate + e-GEMM + i_n GEMM (v5: pipelined B chunks) ----------------
// 512 threads, 8 waves (2M x 4N), M-tile 64. B staged in BK=32 chunks (16KB), double-
// buffered, counted vmcnt(2) — only the final chunk drains to 0. 40 chunks total:
// c 0..31 = Wt_e (t=c>>3), c 32..39 = Wt_in (i_n phase on stashed a-tile).
// Chunk LDS layout [256 rows][4 slots of 16B], slot XOR (R>>1)&3 (2-way conflicts, free).
__global__ __launch_bounds__(512, 4) void k_eagg(
    const u16* __restrict__ acat, int hboff,
    const int* __restrict__ rp2, const int* __restrict__ esrc,
    const u16* __restrict__ Wt_e, const u16* __restrict__ Wt_in,
    const ushort4* __restrict__ cnt2, const float* __restrict__ b_e,
    const float* __restrict__ b_ih512,
    u16* __restrict__ acat_out, u16* __restrict__ inb) {
  __shared__ __align__(16) char Ss[EM * 512];   // 32KB: [64 rows][256 k] bf16, XOR-swizzled
  __shared__ __align__(16) char BsB[2][16384];  // 2 x 16KB B chunks
  __shared__ int Es[ECAP];
  __shared__ int Rp[257];
  const int tid = threadIdx.x;
  const int wv = tid >> 6, l = tid & 63;
  const int hw = tid >> 5, lw = tid & 31;
  const int m0 = blockIdx.x * EM;
  const int fr = l & 15, kq = l >> 4;
  const int wm = (wv >> 2) * 32, wn = (wv & 3) * 64;

  const int base4 = m0 * 4;
  const int e0 = rp2[base4];
  for (int i = tid; i <= 256; i += 512) {
    int idx = base4 + i;
    if (idx > NT4) idx = NT4;
    Rp[i] = rp2[idx] - e0;
  }
  {
    int idxe = base4 + 256;
    if (idxe > NT4) idxe = NT4;
    int ecnt = rp2[idxe] - e0;
    int ecl = ecnt < ECAP ? ecnt : ECAP;
    for (int i = tid; i < ecl; i += 512) Es[i] = esrc[e0 + i] * 768 + hboff;
  }

  // chunk c source: c<32 -> Wt_e[t=c>>3], else Wt_in; k-window (c&7)*32
  auto stageB = [&](int buf, int c) {
    const u16* W = (c < 32) ? (Wt_e + ((size_t)(c >> 3) << 16)) : Wt_in;
    int kbase = (c & 7) << 5;
#pragma unroll
    for (int p = 0; p < 2; ++p) {
      int i = p * 512 + tid;
      int row = i >> 2, slot = i & 3;
      load_lds16(W + (size_t)row * 256 + kbase + ((slot ^ ((row >> 1) & 3)) << 3),
                 BsB[buf] + p * 8192 + wv * 1024);
    }
  };

  __syncthreads();  // Rp/Es visible
  stageB(0, 0);

  f32x4 acc[2][4];
#pragma unroll
  for (int m = 0; m < 2; ++m)
#pragma unroll
    for (int n = 0; n < 4; ++n) acc[m][n] = (f32x4){0.f, 0.f, 0.f, 0.f};

  for (int t = 0; t < 4; ++t) {
    // ---- gather: half-wave hw owns rows hw*4..hw*4+3, round-robin ----
    // (prev t's MFMA finished at its last chunk's trailing barrier -> Ss overwrite safe)
    int cc[4], ee[4];
#pragma unroll
    for (int rr = 0; rr < 4; ++rr) {
      int li = (hw * 4 + rr) * 4 + t;
      cc[rr] = Rp[li];
      ee[rr] = Rp[li + 1];
    }
    float ar[4][8];
#pragma unroll
    for (int rr = 0; rr < 4; ++rr)
#pragma unroll
      for (int q = 0; q < 8; ++q) ar[rr][q] = 0.f;
    bool more = (cc[0] < ee[0]) | (cc[1] < ee[1]) | (cc[2] < ee[2]) | (cc[3] < ee[3]);
    while (more) {
      u16x8 v[4];
      bool p[4];
#pragma unroll
      for (int rr = 0; rr < 4; ++rr) {
        p[rr] = cc[rr] < ee[rr];
        if (p[rr]) {
          int rel = cc[rr];
          int off = (rel < ECAP) ? Es[rel] : (esrc[e0 + rel] * 768 + hboff);
          v[rr] = *(const u16x8*)(acat + (size_t)off + lw * 8);
        }
      }
#pragma unroll
      for (int rr = 0; rr < 4; ++rr) {
        if (p[rr]) {
#pragma unroll
          for (int q = 0; q < 8; ++q) ar[rr][q] += b2f(v[rr][q]);
          cc[rr]++;
        }
      }
      more = (cc[0] < ee[0]) | (cc[1] < ee[1]) | (cc[2] < ee[2]) | (cc[3] < ee[3]);
    }
#pragma unroll
    for (int rr = 0; rr < 4; ++rr) {
      int row = hw * 4 + rr;
      u16x8 o;
#pragma unroll
      for (int q = 0; q < 8; ++q) o[q] = f2b(ar[rr][q]);
      *(u16x8*)(Ss + row * 512 + ((lw * 16) ^ ((row & 7) << 4))) = o;
    }
    asm volatile("s_waitcnt lgkmcnt(0)" ::: "memory");  // own Ss writes drained
    __builtin_amdgcn_sched_barrier(0);

    // ---- pipelined MFMA over 8 chunks of this t ----
    for (int kc = 0; kc < 8; ++kc) {
      const int c = t * 8 + kc;
      const int buf = c & 1;
      stageB(buf ^ 1, c + 1);                         // c<31 always has next
      asm volatile("s_waitcnt vmcnt(2)" ::: "memory");  // chunk c landed
      __builtin_amdgcn_s_barrier();                   // publishes Ss (kc=0) + Bs chunk
      __builtin_amdgcn_sched_barrier(0);
      const char* BsC = BsB[buf];
      const int ka2 = (kc << 6) + (kq << 4);
      bf16x8 af[2], bfr[4];
#pragma unroll
      for (int m = 0; m < 2; ++m) {
        int R = wm + m * 16 + fr;
        af[m] = *(const bf16x8*)(Ss + R * 512 + (ka2 ^ ((R & 7) << 4)));
      }
#pragma unroll
      for (int n = 0; n < 4; ++n) {
        int R = wn + n * 16 + fr;
        bfr[n] = *(const bf16x8*)(BsC + R * 64 + ((kq ^ ((R >> 1) & 3)) << 4));
      }
#pragma unroll
      for (int m = 0; m < 2; ++m)
#pragma unroll
        for (int n = 0; n < 4; ++n)
          acc[m][n] = __builtin_amdgcn_mfma_f32_16x16x32_bf16(af[m], bfr[n], acc[m][n], 0, 0, 0);
      asm volatile("s_waitcnt lgkmcnt(0)" ::: "memory");
      __builtin_amdgcn_sched_barrier(0);
      __builtin_amdgcn_s_barrier();  // all waves done with this chunk + Ss stable
    }
  }

  // ---- epilogue-e: bias, write ab, stash a (bf16) into Ss ----
  float bev[4][4];
#pragma unroll
  for (int n = 0; n < 4; ++n)
#pragma unroll
    for (int t = 0; t < 4; ++t) bev[n][t] = b_e[t * 256 + wn + n * 16 + fr];
#pragma unroll
  for (int m = 0; m < 2; ++m) {
#pragma unroll
    for (int j = 0; j < 4; ++j) {
      int r = wm + m * 16 + kq * 4 + j;
      int v = m0 + r;
      ushort4 c4 = cnt2[v];
      float c0 = c4.x, c1 = c4.y, c2 = c4.z, c3 = c4.w;
#pragma unroll
      for (int n = 0; n < 4; ++n) {
        int col = wn + n * 16 + fr;
        float val = acc[m][n][j] + c0 * bev[n][0] + c1 * bev[n][1] + c2 * bev[n][2] + c3 * bev[n][3];
        u16 vb = f2b(val);
        acat_out[(size_t)v * 768 + 256 + col] = vb;
        *(u16*)(Ss + r * 512 + ((col * 2) ^ ((r & 7) << 4))) = vb;
      }
    }
  }
#pragma unroll
  for (int m = 0; m < 2; ++m)
#pragma unroll
    for (int n = 0; n < 4; ++n) acc[m][n] = (f32x4){0.f, 0.f, 0.f, 0.f};
  asm volatile("s_waitcnt lgkmcnt(0)" ::: "memory");  // stash writes drained
  __builtin_amdgcn_sched_barrier(0);

  // ---- i_n phase: 8 chunks (c = 32..39) on stashed a-tile ----
  for (int kc = 0; kc < 8; ++kc) {
    const int c = 32 + kc;
    const int buf = c & 1;
    if (kc < 7) {
      stageB(buf ^ 1, c + 1);
      asm volatile("s_waitcnt vmcnt(2)" ::: "memory");
    } else {
      asm volatile("s_waitcnt vmcnt(0)" ::: "memory");
    }
    __builtin_amdgcn_s_barrier();  // publishes stash (kc=0) + Bs chunk
    __builtin_amdgcn_sched_barrier(0);
    const char* BsC = BsB[buf];
    const int ka2 = (kc << 6) + (kq << 4);
    bf16x8 af[2], bfr[4];
#pragma unroll
    for (int m = 0; m < 2; ++m) {
      int R = wm + m * 16 + fr;
      af[m] = *(const bf16x8*)(Ss + R * 512 + (ka2 ^ ((R & 7) << 4)));
    }
#pragma unroll
    for (int n = 0; n < 4; ++n) {
      int R = wn + n * 16 + fr;
      bfr[n] = *(const bf16x8*)(BsC + R * 64 + ((kq ^ ((R >> 1) & 3)) << 4));
    }
#pragma unroll
    for (int m = 0; m < 2; ++m)
#pragma unroll
      for (int n = 0; n < 4; ++n)
        acc[m][n] = __builtin_amdgcn_mfma_f32_16x16x32_bf16(af[m], bfr[n], acc[m][n], 0, 0, 0);
    asm volatile("s_waitcnt lgkmcnt(0)" ::: "memory");
    __builtin_amdgcn_sched_barrier(0);
    __builtin_amdgcn_s_barrier();
  }

  float bi[4];
#pragma unroll
  for (int n = 0; n < 4; ++n) bi[n] = b_ih512[wn + n * 16 + fr];
#pragma unroll
  for (int m = 0; m < 2; ++m) {
#pragma unroll
    for (int j = 0; j < 4; ++j) {
      int v = m0 + wm + m * 16 + kq * 4 + j;
#pragma unroll
      for (int n = 0; n < 4; ++n) {
        int col = wn + n * 16 + fr;
        inb[(size_t)v * 256 + col] = f2b(acc[m][n][j] + bi[n]);
      }
    }
  }
}

// ---------------- GEMM: BM=64, BN=256, BK=64, 512 threads, DOUBLE-BUFFERED (r10) ----------
template <int MODE>
__global__ __launch_bounds__(512, 2) void k_gemm2(
    const u16* __restrict__ A, int lda, int K,
    const u16* __restrict__ Bt, const float* __restrict__ bias,
    u16* __restrict__ C, int ldc,
    const u16* __restrict__ rzb, const u16* __restrict__ inb,
    const u16* __restrict__ hold, u16* __restrict__ hnew) {
  __shared__ __align__(16) char AsB[2][64 * 128];   // 2 x 8KB
  __shared__ __align__(16) char BsB[2][256 * 128];  // 2 x 32KB
  const int tid = threadIdx.x;
  const int wv = tid >> 6, l = tid & 63;
  const int m0 = blockIdx.y * 64, n0 = blockIdx.x * 256;
  const int fr = l & 15, kq = l >> 4;
  const int wm = (wv >> 2) * 32, wn = (wv & 3) * 64;
  const int arow = tid >> 3, acl = tid & 7;

  f32x4 acc[2][4];
#pragma unroll
  for (int m = 0; m < 2; ++m)
#pragma unroll
    for (int n = 0; n < 4; ++n) acc[m][n] = (f32x4){0.f, 0.f, 0.f, 0.f};

  auto stage = [&](int buf, int k0) {
    load_lds16(A + (size_t)(m0 + arow) * lda + k0 + ((acl ^ (arow & 7)) << 3),
               AsB[buf] + wv * 1024);
#pragma unroll
    for (int p = 0; p < 4; ++p) {
      int brow = p * 64 + arow;
      load_lds16(Bt + (size_t)(n0 + brow) * K + k0 + ((acl ^ (brow & 7)) << 3),
                 BsB[buf] + p * 8192 + wv * 1024);
    }
  };

  stage(0, 0);
  const int NK = K >> 6;
  for (int ki = 0; ki < NK; ++ki) {
    const int cur = ki & 1;
    if (ki + 1 < NK) {
      stage(cur ^ 1, (ki + 1) << 6);
      asm volatile("s_waitcnt vmcnt(5)" ::: "memory");
    } else {
      asm volatile("s_waitcnt vmcnt(0)" ::: "memory");
    }
    __builtin_amdgcn_s_barrier();
    __builtin_amdgcn_sched_barrier(0);
    const char* As = AsB[cur];
    const char* Bs = BsB[cur];
#pragma unroll
    for (int kk = 0; kk < 64; kk += 32) {
      bf16x8 af[2], bfr[4];
      int kb = (kk + kq * 8) * 2;
#pragma unroll
      for (int m = 0; m < 2; ++m) {
        int R = wm + m * 16 + fr;
        af[m] = *(const bf16x8*)(As + R * 128 + (kb ^ ((R & 7) << 4)));
      }
#pragma unroll
      for (int n = 0; n < 4; ++n) {
        int R = wn + n * 16 + fr;
        bfr[n] = *(const bf16x8*)(Bs + R * 128 + (kb ^ ((R & 7) << 4)));
      }
#pragma unroll
      for (int m = 0; m < 2; ++m)
#pragma unroll
        for (int n = 0; n < 4; ++n)
          acc[m][n] = __builtin_amdgcn_mfma_f32_16x16x32_bf16(af[m], bfr[n], acc[m][n], 0, 0, 0);
    }
    asm volatile("s_waitcnt lgkmcnt(0)" ::: "memory");
    __builtin_amdgcn_sched_barrier(0);
    __builtin_amdgcn_s_barrier();
  }

#pragma unroll
  for (int m = 0; m < 2; ++m) {
#pragma unroll
    for (int j = 0; j < 4; ++j) {
      int row = m0 + wm + m * 16 + kq * 4 + j;
#pragma unroll
      for (int n = 0; n < 4; ++n) {
        int col = n0 + wn + n * 16 + fr;
        float v = acc[m][n][j] + bias[col];
        if (MODE == 1) {
          C[(size_t)row * ldc + col] = f2b(1.f / (1.f + expf(-v)));
        } else {
          float r = b2f(rzb[(size_t)row * 512 + col]);
          float z = b2f(rzb[(size_t)row * 512 + 256 + col]);
          float in_ = b2f(inb[(size_t)row * 256 + col]);
          float ho = b2f(hold[(size_t)row * 768 + col]);
          float ng = tanhf(in_ + r * v);
          hnew[(size_t)row * 768 + col] = f2b((1.f - z) * ng + z * ho);
        }
      }
    }
  }
}

// ---------------- pooling + head ----------------
__global__ __launch_bounds__(256) void k_pool(const u16* __restrict__ hb, const float* __restrict__ feat,
                                              const int* __restrict__ gstart, float* __restrict__ pooled) {
  int g = blockIdx.x, ch = blockIdx.y, t = threadIdx.x;
  int s = gstart[g], e = gstart[g + 1];
  int tot = e - s;
  int per = (tot + PCH - 1) / PCH;
  int ns = s + ch * per;
  int ne = ns + per < e ? ns + per : e;
  if (ns >= ne) return;
  int c = t << 2;
  float a0 = 0.f, a1 = 0.f, a2 = 0.f, a3 = 0.f;
  if (c < 256) {
    for (int n = ns; n < ne; ++n) {
      ushort4 u = *(const ushort4*)(hb + (size_t)n * 768 + c);
      a0 += b2f(u.x); a1 += b2f(u.y); a2 += b2f(u.z); a3 += b2f(u.w);
    }
  } else {
    for (int n = ns; n < ne; ++n) {
      float4 v = *(const float4*)(feat + (size_t)n * 1024 + c);
      a0 += v.x; a1 += v.y; a2 += v.z; a3 += v.w;
    }
  }
  atomicAdd(&pooled[g * 1024 + c], a0);
  atomicAdd(&pooled[g * 1024 + c + 1], a1);
  atomicAdd(&pooled[g * 1024 + c + 2], a2);
  atomicAdd(&pooled[g * 1024 + c + 3], a3);
}

__global__ __launch_bounds__(256) void k_head(const float* __restrict__ pooled,
                                              const int* __restrict__ gstart,
                                              const float* __restrict__ W1, const float* __restrict__ b1,
                                              const float* __restrict__ W2, const float* __restrict__ b2,
                                              float* __restrict__ out) {
  __shared__ float sp[1024];
  __shared__ float red[256];
  int g = blockIdx.x, t = threadIdx.x;
  float inv = 1.f / fmaxf((float)(gstart[g + 1] - gstart[g]), 1.f);
  for (int i = t; i < 1024; i += 256) sp[i] = pooled[g * 1024 + i] * inv;
  __syncthreads();
  float acc = b1[t];
  for (int k = 0; k < 1024; ++k) acc += sp[k] * W1[k * 256 + t];
  float hc = fmaxf(acc, 0.f);
  red[t] = hc * W2[t];
  __syncthreads();
  for (int s2 = 128; s2 > 0; s2 >>= 1) {
    if (t < s2) red[t] += red[t + s2];
    __syncthreads();
  }
  if (t == 0) out[g] = 1.f / (1.f + expf(-(red[0] + b2[0])));
}

extern "C" void kernel_launch(void* const* d_in, const int* in_sizes, int n_in, void* d_out, int out_size,
                              void* d_ws, size_t ws_size, hipStream_t stream) {
  const float* feat = (const float*)d_in[0];
  const float* W_e = (const float*)d_in[1];
  const float* b_e = (const float*)d_in[2];
  const float* W_ih = (const float*)d_in[3];
  const float* W_hh = (const float*)d_in[4];
  const float* b_ih = (const float*)d_in[5];
  const float* b_hh = (const float*)d_in[6];
  const float* W1 = (const float*)d_in[7];
  const float* b1 = (const float*)d_in[8];
  const float* W2 = (const float*)d_in[9];
  const float* b2 = (const float*)d_in[10];
  const int* src = (const int*)d_in[11];
  const int* dst = (const int*)d_in[12];
  const int* ety = (const int*)d_in[13];
  const int* n2g = (const int*)d_in[14];

  char* p = (char*)d_ws;
  auto alloc = [&](size_t b) { char* r = p; p += (b + 255) & ~(size_t)255; return r; };
  u16* acat = (u16*)alloc((size_t)MPAD * 768 * 2);  // [hbA | ab | hbB]
  u16* rzb = (u16*)alloc((size_t)MPAD * 512 * 2);
  u16* inb = (u16*)alloc((size_t)MPAD * 256 * 2);
  u16* Wt_e = (u16*)alloc(1024 * 256 * 2);
  u16* Wt_rz_ah = (u16*)alloc(512 * 512 * 2);
  u16* Wt_rz_ha = (u16*)alloc(512 * 512 * 2);
  u16* Wt_in = (u16*)alloc(256 * 256 * 2);
  u16* Wt_hn = (u16*)alloc(256 * 256 * 2);
  float* b_rz = (float*)alloc(512 * 4);
  int* deg2 = (int*)alloc((size_t)NT4 * 4);
  int* part = (int*)alloc((size_t)NT4 * 4);
  int* bsum = (int*)alloc((size_t)SCB2 * 4);
  int* boff = (int*)alloc(1025 * 4);
  int* rp2 = (int*)alloc((size_t)(NT4 + 1) * 4);
  int* cursor2 = (int*)alloc((size_t)NT4 * 4);
  int* esrc = (int*)alloc((size_t)NE * 4);
  ushort4* cnt2 = (ushort4*)alloc((size_t)MPAD * 8);
  int* gstart = (int*)alloc((size_t)(NG + 1) * 4);
  float* pooled = (float*)alloc((size_t)NG * 1024 * 4);

  hipMemsetAsync(deg2, 0, (size_t)NT4 * 4, stream);
  hipMemsetAsync(cursor2, 0, (size_t)NT4 * 4, stream);
  hipMemsetAsync(pooled, 0, (size_t)NG * 1024 * 4, stream);

  k_conv_we<<<1024, 256, 0, stream>>>(W_e, Wt_e);
  k_conv_rz<<<1024, 256, 0, stream>>>(W_ih, W_hh, Wt_rz_ah, Wt_rz_ha);
  k_conv_n<<<256, 256, 0, stream>>>(W_ih, Wt_in);
  k_conv_n<<<256, 256, 0, stream>>>(W_hh, Wt_hn);
  k_brz<<<2, 256, 0, stream>>>(b_ih, b_hh, b_rz);
  k_init_h<<<MPAD / 4, 256, 0, stream>>>(feat, acat);
  k_hist<<<(NE + 255) / 256, 256, 0, stream>>>(dst, ety, deg2);
  k_scan1<<<SCB2, 256, 0, stream>>>(deg2, part, bsum);
  k_scan2<<<1, 1024, 0, stream>>>(bsum, boff);
  k_scan3<<<SCB2 + 1, 256, 0, stream>>>(part, boff, rp2);
  k_scatter<<<(NE + 255) / 256, 256, 0, stream>>>(src, dst, ety, rp2, cursor2, esrc);
  k_cnt2<<<(MPAD + 255) / 256, 256, 0, stream>>>(deg2, cnt2);
  k_gstart<<<SCB, 256, 0, stream>>>(n2g, gstart);

  const int GY = MPAD / 64;  // 782
  for (int s = 0; s < NSTEP; ++s) {
    int hboff = (s & 1) ? 512 : 0;
    int hnewoff = 512 - hboff;
    int rzoff = (s & 1) ? 256 : 0;
    const u16* Wrz = (s & 1) ? Wt_rz_ah : Wt_rz_ha;
    // fused: gather-sum h -> S_t; a = sum_t S_t@W_e[t] + cnt*b_e; i_n = a@W_in + b_ih[512:]
    k_eagg<<<MPAD / EM, 512, 0, stream>>>(acat, hboff, rp2, esrc, Wt_e, Wt_in, cnt2, b_e,
                                          b_ih + 512, acat, inb);
    // r,z = sigmoid([a|h] @ Wrz + b_rz)
    k_gemm2<1><<<dim3(2, GY), 512, 0, stream>>>(acat + rzoff, 768, 512, Wrz, b_rz, rzb, 512,
                                                nullptr, nullptr, nullptr, nullptr);
    // h_n GEMM + fused GRU combine -> hnew
    k_gemm2<2><<<dim3(1, GY), 512, 0, stream>>>(acat + hboff, 768, 256, Wt_hn, b_hh + 512,
                                                nullptr, 0, rzb, inb, acat + hboff,
                                                acat + hnewoff);
  }

  // after step 7 (odd), final h is in hbA (offset 0)
  k_pool<<<dim3(NG, PCH), 256, 0, stream>>>(acat, feat, gstart, pooled);
  k_head<<<NG, 256, 0, stream>>>(pooled, gstart, W1, b1, W2, b2, (float*)d_out);
}